// Round 1
// baseline (293.030 us; speedup 1.0000x reference)
//
#include <hip/hip_runtime.h>

// SSIM over 11x11 gaussian-weighted patches.
// pred: [4, 2048, 16, 121, 3] f32   gt: [2048, 16, 121, 3] f32
// out:  [4, 2048, 16] f32
//
// R6: gt-sharing restructure. Each block owns 4 consecutive (N,n_p)
// patches x ALL 4 views = 16 outputs, so the gt chunk (4 patches,
// 5808 B = 363 float4, 16B-aligned) is staged to LDS ONCE and reused by
// all 4 view-groups. This removes the 4x gt re-read (~143 MB of
// L3/HBM read traffic) and converts gt's 24 uncoalesced scalar dword
// loads per thread into coalesced float4 staging. Total read traffic
// drops to the algorithmic minimum (pred 190.3 MB + gt 47.6 MB).
//
// LDS: 23232 (pred) + 5808 (gt) + 512 (W) = 29.5 KB -> 4 blocks/CU kept
// (118 KB < 160 KB). Compute path and reduction order are bit-identical
// to R5: 16 lanes/output, pixel-per-lane, 15 stats via shfl_xor within
// 16-lane groups.

static constexpr int NPATCH         = 2048 * 16;          // 32768 (N * n_p)
static constexpr int PPB            = 4;                  // gt patches per block
static constexpr int NBLK           = NPATCH / PPB;       // 8192 blocks
static constexpr int CHUNK_F4       = PPB * 363 / 4;      // 363 float4 per view-chunk
static constexpr int VIEW_STRIDE_F4 = NPATCH * 363 / 4;   // 2973696 float4 between views

__device__ __constant__ float G11[11] = {
    0.00102838f, 0.00759875f, 0.03600077f, 0.10936070f, 0.21300555f,
    0.26601173f,
    0.21300555f, 0.10936070f, 0.03600077f, 0.00759875f, 0.00102838f
};

__device__ __forceinline__ float red16(float v) {
    v += __shfl_xor(v, 1);
    v += __shfl_xor(v, 2);
    v += __shfl_xor(v, 4);
    v += __shfl_xor(v, 8);
    return v;
}

__global__ __launch_bounds__(256, 4) void ssim_kernel(
    const float* __restrict__ pred, const float* __restrict__ gt,
    float* __restrict__ out)
{
    __shared__ float4 predS4[4 * CHUNK_F4];  // 23232 B: 4 view-chunks
    __shared__ float4 gtS4[CHUNK_F4];        //  5808 B: 1 shared gt chunk
    __shared__ float  W[128];                //   512 B: gaussian weights

    const int t = threadIdx.x;
    const int b = blockIdx.x;

    // ---- stage gt chunk (363 float4), perfectly coalesced ----
    const float4* gsrc = (const float4*)gt + (size_t)b * CHUNK_F4;
    gtS4[t] = gsrc[t];                                  // t < 256 < 363
    if (t < CHUNK_F4 - 256) gtS4[t + 256] = gsrc[t + 256];

    // ---- stage 4 pred view-chunks (363 float4 each), coalesced ----
    const float4* psrc0 = (const float4*)pred + (size_t)b * CHUNK_F4;
    #pragma unroll
    for (int v = 0; v < 4; ++v) {
        const float4* src = psrc0 + (size_t)v * VIEW_STRIDE_F4;
        float4* dst = predS4 + v * CHUNK_F4;
        dst[t] = src[t];
        if (t < CHUNK_F4 - 256) dst[t + 256] = src[t + 256];
    }

    // ---- weight table ----
    if (t < 128) {
        float w = 0.f;
        if (t < 121) {
            const int r = t / 11;
            const int c = t - r * 11;
            w = G11[r] * G11[c];
        }
        W[t] = w;
    }
    __syncthreads();

    // ---- compute: 16 lanes per output, pixel-per-lane ----
    const int lane = t & 15;
    const int grp  = t >> 4;        // 0..15
    const int v    = grp >> 2;      // view 0..3
    const int s    = grp & 3;       // patch-in-block 0..3

    const float* p = (const float*)predS4 + (v * PPB + s) * 363;
    const float* g = (const float*)gtS4 + s * 363;

    float mu1[3] = {0.f, 0.f, 0.f};
    float mu2[3] = {0.f, 0.f, 0.f};
    float s1 [3] = {0.f, 0.f, 0.f};
    float s2 [3] = {0.f, 0.f, 0.f};
    float s12[3] = {0.f, 0.f, 0.f};

    #pragma unroll
    for (int rnd = 0; rnd < 8; ++rnd) {
        const int pix = lane + rnd * 16;               // 0..127
        const float w = W[pix];                        // 0 for pix >= 121
        const int pc  = (pix < 121 ? pix : 120) * 3;   // clamp: in-bounds
        const float pv[3] = {p[pc], p[pc + 1], p[pc + 2]};
        const float gv[3] = {g[pc], g[pc + 1], g[pc + 2]};
        #pragma unroll
        for (int c = 0; c < 3; ++c) {
            const float pvc = pv[c];
            const float gvc = gv[c];
            const float tp = w * pvc;
            const float tg = w * gvc;
            mu1[c] += tp;
            mu2[c] += tg;
            s1 [c] = fmaf(tp, pvc, s1 [c]);
            s2 [c] = fmaf(tg, gvc, s2 [c]);
            s12[c] = fmaf(tp, gvc, s12[c]);
        }
    }

    // reduce the 15 stats across the 16-lane group
    #pragma unroll
    for (int c = 0; c < 3; ++c) {
        mu1[c] = red16(mu1[c]);
        mu2[c] = red16(mu2[c]);
        s1 [c] = red16(s1 [c]);
        s2 [c] = red16(s2 [c]);
        s12[c] = red16(s12[c]);
    }

    if (lane == 0) {
        const float C1 = 1e-4f;   // 0.01^2
        const float C2 = 9e-4f;   // 0.03^2
        float acc = 0.f;
        #pragma unroll
        for (int c = 0; c < 3; ++c) {
            const float m1 = mu1[c], m2 = mu2[c];
            const float m1sq = m1 * m1, m2sq = m2 * m2, m12 = m1 * m2;
            const float sig1 = s1[c]  - m1sq;
            const float sig2 = s2[c]  - m2sq;
            const float sg12 = s12[c] - m12;
            const float num = (2.f * m12 + C1) * (2.f * sg12 + C2);
            const float den = (m1sq + m2sq + C1) * (sig1 + sig2 + C2);
            acc += num / den;
        }
        out[v * NPATCH + b * PPB + s] = acc * (1.f / 3.f);
    }
}

extern "C" void kernel_launch(void* const* d_in, const int* in_sizes, int n_in,
                              void* d_out, int out_size, void* d_ws, size_t ws_size,
                              hipStream_t stream) {
    const float* pred = (const float*)d_in[0];
    const float* gt   = (const float*)d_in[1];
    float* out        = (float*)d_out;
    ssim_kernel<<<NBLK, 256, 0, stream>>>(pred, gt, out);
}